// Round 3
// baseline (216.239 us; speedup 1.0000x reference)
//
#include <hip/hip_runtime.h>

typedef short  bf16x8  __attribute__((ext_vector_type(8)));
typedef float  f32x4   __attribute__((ext_vector_type(4)));
typedef float  f32x16  __attribute__((ext_vector_type(16)));
typedef unsigned short ushort;

__device__ __forceinline__ short f2bf(float f) {
  __bf16 h = (__bf16)f;                 // RNE
  return __builtin_bit_cast(short, h);
}

// ws layout (float offsets):
//   [0        .. 4194304)  gate partials: ks*524288 + b*8192 + gate*2048 + j   (ks 0..7)
//   [4194304  .. 5242880)  y partials:    4194304 + ksy*131072 + b*2048 + j    (ksy 0..7)
//   [5242880  .. )         Abf: bf16 [64][4096] = 262144 ushorts (h | x concat)
#define GATE_PART 0
#define Y_PART    4194304
#define ABF_OFF   5242880

// ---------------------------------------------------------------------------
// Kernel 0: convert A = [h_prev | x] to bf16, row-major [64][4096].
// ---------------------------------------------------------------------------
__global__ __launch_bounds__(256) void lstm_aconv(
    const float* __restrict__ X, const float* __restrict__ H,
    ushort* __restrict__ Abf)
{
  const int t  = blockIdx.x * 256 + threadIdx.x;   // 32768 threads
  const int e0 = t * 8;                            // 8 elems/thread
  const int b  = e0 >> 12;
  const int k  = e0 & 4095;
  const float* src = (k < 2048) ? (H + (size_t)b * 2048 + k)
                                : (X + (size_t)b * 2048 + (k - 2048));
  f32x4 v0 = *(const f32x4*)(src);
  f32x4 v1 = *(const f32x4*)(src + 4);
  bf16x8 o;
  o[0] = f2bf(v0[0]); o[1] = f2bf(v0[1]); o[2] = f2bf(v0[2]); o[3] = f2bf(v0[3]);
  o[4] = f2bf(v1[0]); o[5] = f2bf(v1[1]); o[6] = f2bf(v1[2]); o[7] = f2bf(v1[3]);
  *(bf16x8*)(Abf + e0) = o;
}

// ---------------------------------------------------------------------------
// Per-wave skinny GEMM, D=4-deep register-ring software pipeline.
// C[64 x 32] += A[64 x K] * W[K x 32], K = NSTEPS*16, mfma_f32_32x32x16_bf16.
// Fully unrolled: every ring index is compile-time (rule #20), so LLVM's
// waitcnt pass emits counted vmcnt (steps s+1..s+3 stay in flight while
// step s computes). No LDS, no barriers.
// ---------------------------------------------------------------------------
template<int NSTEPS>
__device__ __forceinline__ void gemm_wave(
    const float* __restrict__ wbase,
    const ushort* __restrict__ a0p, const ushort* __restrict__ a1p,
    float bias, float* __restrict__ outBase, int outStride, int lane)
{
  constexpr int D = 4;                      // pipeline depth (power of 2)
  const int kg8 = (lane >> 5) << 3;         // k sub-group offset (0 or 8)
  const float* wcol = wbase + (size_t)kg8 * 2048;

  f32x16 acc0, acc1;
  #pragma unroll
  for (int r = 0; r < 16; ++r) { acc0[r] = bias; acc1[r] = bias; }

  float wf[D][8]; bf16x8 a0r[D], a1r[D];

  // prologue: issue D steps' worth of loads back-to-back (40 loads in flight)
  #pragma unroll
  for (int d = 0; d < D; ++d) {
    const float* p = wcol + (size_t)(d * 16) * 2048;
    #pragma unroll
    for (int i = 0; i < 8; ++i) wf[d][i] = p[(size_t)i * 2048];
    a0r[d] = *(const bf16x8*)(a0p + d * 16);
    a1r[d] = *(const bf16x8*)(a1p + d * 16);
  }

  #pragma unroll
  for (int s = 0; s < NSTEPS; ++s) {
    const int slot = s & (D - 1);           // compile-time under full unroll
    bf16x8 bf;
    #pragma unroll
    for (int i = 0; i < 8; ++i) bf[i] = f2bf(wf[slot][i]);
    acc0 = __builtin_amdgcn_mfma_f32_32x32x16_bf16(a0r[slot], bf, acc0, 0, 0, 0);
    acc1 = __builtin_amdgcn_mfma_f32_32x32x16_bf16(a1r[slot], bf, acc1, 0, 0, 0);
    if (s + D < NSTEPS) {                   // refill slot with step s+D
      const float* p = wcol + (size_t)((s + D) * 16) * 2048;
      #pragma unroll
      for (int i = 0; i < 8; ++i) wf[slot][i] = p[(size_t)i * 2048];
      a0r[slot] = *(const bf16x8*)(a0p + (s + D) * 16);
      a1r[slot] = *(const bf16x8*)(a1p + (s + D) * 16);
    }
  }

  // D layout (32x32): col = lane&31, row = (r&3) + 8*(r>>2) + 4*(lane>>5)
  const int rbase = 4 * (lane >> 5);
  #pragma unroll
  for (int r = 0; r < 16; ++r) {
    const int row = (r & 3) + 8 * (r >> 2) + rbase;
    outBase[(size_t)row * outStride]        = acc0[r];
    outBase[(size_t)(row + 32) * outStride] = acc1[r];
  }
}

// ---------------------------------------------------------------------------
// Kernel 1: 2560 independent waves.
//   w < 2048 : gate job.  gate=w>>9, ks=(w>>6)&7, jt=w&63  (K=512, 32 steps)
//   w >= 2048: y job.     ksy=(w-2048)>>6, jt=(w-2048)&63  (K=256, 16 steps)
// Blocks 0..511 are pure gate, 512..639 pure y (no intra-block divergence).
// ---------------------------------------------------------------------------
__global__ __launch_bounds__(256, 3) void lstm_gemm(
    const float* __restrict__ Wfh, const float* __restrict__ Wfx, const float* __restrict__ bfp,
    const float* __restrict__ Wih, const float* __restrict__ Wix, const float* __restrict__ bip,
    const float* __restrict__ Woh, const float* __restrict__ Wox, const float* __restrict__ bop,
    const float* __restrict__ Wch, const float* __restrict__ Wcx, const float* __restrict__ bcp,
    const float* __restrict__ Wy,  const float* __restrict__ by,
    float* __restrict__ ws)
{
  const int lane = threadIdx.x & 63;
  const int w    = blockIdx.x * 4 + (threadIdx.x >> 6);
  const int n    = lane & 31;
  const int kg8  = (lane >> 5) << 3;
  const ushort* Abf = (const ushort*)(ws + ABF_OFF);

  if (w < 2048) {
    const int gate = w >> 9;
    const int ks   = (w >> 6) & 7;
    const int jt   = w & 63;
    const int j0   = jt * 32;

    const float *Wg_h, *Wg_x, *bg;
    if      (gate == 0) { Wg_h = Wfh; Wg_x = Wfx; bg = bfp; }
    else if (gate == 1) { Wg_h = Wih; Wg_x = Wix; bg = bip; }
    else if (gate == 2) { Wg_h = Wch; Wg_x = Wcx; bg = bcp; }
    else                { Wg_h = Woh; Wg_x = Wox; bg = bop; }

    const float* Wmat = (ks < 4) ? Wg_h : Wg_x;
    const int krow0 = (ks & 3) * 512;          // row within that matrix
    const int aK0   = ks * 512;                // col in concat A
    const float bias = (ks == 0) ? bg[j0 + n] : 0.f;

    const float* wbase = Wmat + (size_t)krow0 * 2048 + j0 + n;
    const ushort* a0p = Abf + (size_t)(lane & 31) * 4096 + aK0 + kg8;
    const ushort* a1p = a0p + (size_t)32 * 4096;
    float* outBase = ws + GATE_PART + (size_t)ks * 524288 + gate * 2048 + j0 + n;

    gemm_wave<32>(wbase, a0p, a1p, bias, outBase, 8192, lane);
  } else {
    const int yi  = w - 2048;
    const int ksy = yi >> 6;
    const int jt  = yi & 63;
    const int j0  = jt * 32;

    const int krow0 = ksy * 256;
    const float bias = (ksy == 0) ? by[j0 + n] : 0.f;

    const float* wbase = Wy + (size_t)krow0 * 2048 + j0 + n;
    const ushort* a0p = Abf + (size_t)(lane & 31) * 4096 + krow0 + kg8;  // y uses h
    const ushort* a1p = a0p + (size_t)32 * 4096;
    float* outBase = ws + Y_PART + (size_t)ksy * 131072 + j0 + n;

    gemm_wave<16>(wbase, a0p, a1p, bias, outBase, 2048, lane);
  }
}

// ---------------------------------------------------------------------------
// Kernel 2: reduce K-split partials, apply LSTM nonlinearity, pack [y|h|c].
// ---------------------------------------------------------------------------
__device__ __forceinline__ float fsigmoid(float x) {
  return 1.f / (1.f + __expf(-x));
}
__device__ __forceinline__ float ftanh(float x) {
  return 1.f - 2.f / (1.f + __expf(2.f * x));   // exact at +-inf, fine for bf16 tol
}

__global__ __launch_bounds__(64) void lstm_combine(
    const float* __restrict__ ws, const float* __restrict__ c_prev,
    float* __restrict__ out)
{
  const int t  = blockIdx.x * 64 + threadIdx.x;  // 0..32767
  const int b  = t >> 9;
  const int j4 = (t & 511) * 4;

  f32x4 g[4];
  #pragma unroll
  for (int gg = 0; gg < 4; ++gg) {
    f32x4 s = (f32x4){0.f, 0.f, 0.f, 0.f};
    #pragma unroll
    for (int ks = 0; ks < 8; ++ks)
      s += *(const f32x4*)(ws + GATE_PART + (size_t)ks * 524288 + (size_t)b * 8192 + gg * 2048 + j4);
    g[gg] = s;
  }
  f32x4 ysum = (f32x4){0.f, 0.f, 0.f, 0.f};
  #pragma unroll
  for (int ks = 0; ks < 8; ++ks)
    ysum += *(const f32x4*)(ws + Y_PART + (size_t)ks * 131072 + (size_t)b * 2048 + j4);

  const f32x4 cp = *(const f32x4*)(c_prev + (size_t)b * 2048 + j4);
  f32x4 hF, cF;
  #pragma unroll
  for (int e = 0; e < 4; ++e) {
    float f  = fsigmoid(g[0][e]);
    float i  = fsigmoid(g[1][e]);
    float ct = ftanh(g[2][e]);
    float o  = fsigmoid(g[3][e]);
    float c  = f * cp[e] + i * ct;
    cF[e] = c;
    hF[e] = o * ftanh(c);
  }
  float* ob = out + (size_t)b * 6144;
  *(f32x4*)(ob + j4)        = ysum;   // y = h_prev @ Wy + by
  *(f32x4*)(ob + 2048 + j4) = hF;     // h
  *(f32x4*)(ob + 4096 + j4) = cF;     // c
}

extern "C" void kernel_launch(void* const* d_in, const int* in_sizes, int n_in,
                              void* d_out, int out_size, void* d_ws, size_t ws_size,
                              hipStream_t stream)
{
  const float* X   = (const float*)d_in[0];
  const float* H   = (const float*)d_in[1];
  const float* Cp  = (const float*)d_in[2];
  const float* Wfh = (const float*)d_in[3];
  const float* Wfx = (const float*)d_in[4];
  const float* bfp = (const float*)d_in[5];
  const float* Wih = (const float*)d_in[6];
  const float* Wix = (const float*)d_in[7];
  const float* bip = (const float*)d_in[8];
  const float* Woh = (const float*)d_in[9];
  const float* Wox = (const float*)d_in[10];
  const float* bop = (const float*)d_in[11];
  const float* Wch = (const float*)d_in[12];
  const float* Wcx = (const float*)d_in[13];
  const float* bcp = (const float*)d_in[14];
  const float* Wy  = (const float*)d_in[15];
  const float* by  = (const float*)d_in[16];
  float* ws  = (float*)d_ws;
  float* out = (float*)d_out;

  lstm_aconv<<<128, 256, 0, stream>>>(X, H, (ushort*)(ws + ABF_OFF));
  lstm_gemm<<<640, 256, 0, stream>>>(Wfh, Wfx, bfp, Wih, Wix, bip,
                                     Woh, Wox, bop, Wch, Wcx, bcp, Wy, by, ws);
  lstm_combine<<<512, 64, 0, stream>>>(ws, Cp, out);
}

// Round 4
// 203.209 us; speedup vs baseline: 1.0641x; 1.0641x over previous
//
#include <hip/hip_runtime.h>

#define GAS __attribute__((address_space(1)))
#define LAS __attribute__((address_space(3)))

typedef short  bf16x8  __attribute__((ext_vector_type(8)));
typedef float  f32x4   __attribute__((ext_vector_type(4)));
typedef float  f32x16  __attribute__((ext_vector_type(16)));
typedef unsigned short ushort;

__device__ __forceinline__ short f2bf(float f) {
  __bf16 h = (__bf16)f;                 // RNE
  return __builtin_bit_cast(short, h);
}

// ws layout (float offsets):
//   [0        .. 4194304)  gate partials: ks*524288 + b*8192 + gate*2048 + j   (ks 0..7)
//   [4194304  .. 5242880)  y partials:    4194304 + ksy*131072 + b*2048 + j    (ksy 0..7)
//   [5242880  .. )         Abf: bf16 [64][4096] = 262144 ushorts (h | x concat)
#define GATE_PART 0
#define Y_PART    4194304
#define ABF_OFF   5242880

// ---------------------------------------------------------------------------
// Kernel 0: convert A = [h_prev | x] to bf16, row-major [64][4096].
// ---------------------------------------------------------------------------
__global__ __launch_bounds__(256) void lstm_aconv(
    const float* __restrict__ X, const float* __restrict__ H,
    ushort* __restrict__ Abf)
{
  const int t  = blockIdx.x * 256 + threadIdx.x;   // 32768 threads
  const int e0 = t * 8;
  const int b  = e0 >> 12;
  const int k  = e0 & 4095;
  const float* src = (k < 2048) ? (H + (size_t)b * 2048 + k)
                                : (X + (size_t)b * 2048 + (k - 2048));
  f32x4 v0 = *(const f32x4*)(src);
  f32x4 v1 = *(const f32x4*)(src + 4);
  bf16x8 o;
  o[0] = f2bf(v0[0]); o[1] = f2bf(v0[1]); o[2] = f2bf(v0[2]); o[3] = f2bf(v0[3]);
  o[4] = f2bf(v1[0]); o[5] = f2bf(v1[1]); o[6] = f2bf(v1[2]); o[7] = f2bf(v1[3]);
  *(bf16x8*)(Abf + e0) = o;
}

// ---------------------------------------------------------------------------
// Kernel 1: LDS-staged skinny GEMM.
// 640 blocks x 256 thr (4 waves). Block job:
//   bid < 512 : gate job. gate=bid>>7, stripe=(bid>>3)&15, ks=bid&7.
//               cols j0=stripe*128 of gate, K rows ks*512..+512 (8 BK=64 chunks)
//   bid >= 512: y job.    stripe=(yi>>3), ksy=yi&7. K rows ksy*256..+256 (4 chunks)
// W chunk [64k x 128col] f32 staged linear via global_load_lds (dwordx4);
// A chunk [64b x 64k] bf16 staged XOR-swizzled (pre-swizzled source).
// Double-buffered, counted vmcnt(10), raw barriers. MFMA 32x32x16 bf16.
// ---------------------------------------------------------------------------
__global__ __launch_bounds__(256, 2) void lstm_gemm(
    const float* __restrict__ Wfh, const float* __restrict__ Wfx, const float* __restrict__ bfp,
    const float* __restrict__ Wih, const float* __restrict__ Wix, const float* __restrict__ bip,
    const float* __restrict__ Woh, const float* __restrict__ Wox, const float* __restrict__ bop,
    const float* __restrict__ Wch, const float* __restrict__ Wcx, const float* __restrict__ bcp,
    const float* __restrict__ Wy,  const float* __restrict__ by,
    float* __restrict__ ws)
{
  __shared__ float  ldsW[2][64 * 128];   // 64 KB
  __shared__ ushort ldsA[2][64 * 64];    // 16 KB

  const int tid  = threadIdx.x;
  const int lane = tid & 63;
  const int widx = tid >> 6;
  const int n    = lane & 31;            // MFMA col (B) / batch row (A)
  const int kg8  = (lane >> 5) << 3;     // k sub-slice (0 or 8)
  const int j0w  = widx * 32;            // wave's col offset within 128-stripe
  const ushort* Abf = (const ushort*)(ws + ABF_OFF);

  const int bid = blockIdx.x;
  const float* Wmat; int krow0m, aK0, nch;
  float bias; float* outBase; int outStride;

  if (bid < 512) {
    const int gate   = bid >> 7;
    const int stripe = (bid >> 3) & 15;
    const int ks     = bid & 7;
    const int j0     = stripe * 128;
    const float *Wg_h, *Wg_x, *bg;
    if      (gate == 0) { Wg_h = Wfh; Wg_x = Wfx; bg = bfp; }
    else if (gate == 1) { Wg_h = Wih; Wg_x = Wix; bg = bip; }
    else if (gate == 2) { Wg_h = Wch; Wg_x = Wcx; bg = bcp; }
    else                { Wg_h = Woh; Wg_x = Wox; bg = bop; }
    Wmat    = ((ks < 4) ? Wg_h : Wg_x) + j0;      // fold col offset into base
    krow0m  = (ks & 3) * 512;
    aK0     = ks * 512;
    nch     = 8;
    bias    = (ks == 0) ? bg[j0 + j0w + n] : 0.f;
    outBase = ws + GATE_PART + (size_t)ks * 524288 + (size_t)gate * 2048 + j0 + j0w + n;
    outStride = 8192;
  } else {
    const int yi     = bid - 512;
    const int stripe = yi >> 3;
    const int ksy    = yi & 7;
    const int j0     = stripe * 128;
    Wmat    = Wy + j0;
    krow0m  = ksy * 256;
    aK0     = krow0m;                    // y uses h (first 2048 of concat A)
    nch     = 4;
    bias    = (ksy == 0) ? by[j0 + j0w + n] : 0.f;
    outBase = ws + Y_PART + (size_t)ksy * 131072 + j0 + j0w + n;
    outStride = 2048;
  }

  // --- stage W chunk [64][128] f32, linear LDS (coalesced 512B rows) ---
  auto stageW = [&](int buf, int krow) {
    #pragma unroll
    for (int i = 0; i < 8; ++i) {
      const int r = i * 8 + widx * 2 + (lane >> 5);
      const float* src = Wmat + (size_t)(krow + r) * 2048 + (lane & 31) * 4;
      float* dst = &ldsW[buf][(i * 8 + widx * 2) * 128];   // wave-uniform base
      __builtin_amdgcn_global_load_lds((const GAS unsigned*)src,
                                       (LAS unsigned*)dst, 16, 0, 0);
    }
  };
  // --- stage A chunk [64][64] bf16, XOR-swizzled via pre-swizzled source ---
  auto stageA = [&](int buf, int aK) {
    #pragma unroll
    for (int i = 0; i < 2; ++i) {
      const int b    = i * 32 + widx * 8 + (lane >> 3);
      const int coff = (((lane & 7) * 16) ^ ((b & 7) << 4)) >> 1;  // elem offset
      const ushort* src = Abf + (size_t)b * 4096 + aK + coff;
      ushort* dst = &ldsA[buf][(i * 32 + widx * 8) * 64];          // wave-uniform
      __builtin_amdgcn_global_load_lds((const GAS unsigned*)src,
                                       (LAS unsigned*)dst, 16, 0, 0);
    }
  };

  f32x16 acc0, acc1;
  #pragma unroll
  for (int r = 0; r < 16; ++r) { acc0[r] = bias; acc1[r] = bias; }

  stageW(0, krow0m); stageA(0, aK0);

  for (int ch = 0; ch < nch; ++ch) {
    if (ch + 1 < nch) {
      stageW((ch + 1) & 1, krow0m + (ch + 1) * 64);
      stageA((ch + 1) & 1, aK0 + (ch + 1) * 64);
      asm volatile("s_waitcnt vmcnt(10)" ::: "memory");   // chunk ch landed
    } else {
      asm volatile("s_waitcnt vmcnt(0)" ::: "memory");
    }
    __builtin_amdgcn_s_barrier();                          // chunk ch visible

    {  // compute chunk ch: 4 K-steps of 16
      const int buf = ch & 1;
      const char* ab = (const char*)&ldsA[buf][0];
      #pragma unroll
      for (int k0 = 0; k0 < 64; k0 += 16) {
        const int kk = k0 + kg8;
        float wf[8];
        #pragma unroll
        for (int i = 0; i < 8; ++i)
          wf[i] = ldsW[buf][(kk + i) * 128 + j0w + n];     // 2-way bank (free)
        bf16x8 bfrag;
        #pragma unroll
        for (int i = 0; i < 8; ++i) bfrag[i] = f2bf(wf[i]);
        bf16x8 a0 = *(const bf16x8*)(ab + (((n)      * 128 + kk * 2) ^ ((n & 7) << 4)));
        bf16x8 a1 = *(const bf16x8*)(ab + (((n + 32) * 128 + kk * 2) ^ ((n & 7) << 4)));
        acc0 = __builtin_amdgcn_mfma_f32_32x32x16_bf16(a0, bfrag, acc0, 0, 0, 0);
        acc1 = __builtin_amdgcn_mfma_f32_32x32x16_bf16(a1, bfrag, acc1, 0, 0, 0);
      }
    }
    __builtin_amdgcn_s_barrier();     // all waves done reading buf before restage
  }

  // D layout (32x32): col = lane&31, row = (r&3) + 8*(r>>2) + 4*(lane>>5)
  const int rbase = 4 * (lane >> 5);
  #pragma unroll
  for (int r = 0; r < 16; ++r) {
    const int row = (r & 3) + 8 * (r >> 2) + rbase;
    outBase[(size_t)row * outStride]        = acc0[r];
    outBase[(size_t)(row + 32) * outStride] = acc1[r];
  }
}

// ---------------------------------------------------------------------------
// Kernel 2: reduce K-split partials, apply LSTM nonlinearity, pack [y|h|c].
// ---------------------------------------------------------------------------
__device__ __forceinline__ float fsigmoid(float x) {
  return 1.f / (1.f + __expf(-x));
}
__device__ __forceinline__ float ftanh(float x) {
  return 1.f - 2.f / (1.f + __expf(2.f * x));
}

__global__ __launch_bounds__(64) void lstm_combine(
    const float* __restrict__ ws, const float* __restrict__ c_prev,
    float* __restrict__ out)
{
  const int t  = blockIdx.x * 64 + threadIdx.x;  // 0..32767
  const int b  = t >> 9;
  const int j4 = (t & 511) * 4;

  f32x4 g[4];
  #pragma unroll
  for (int gg = 0; gg < 4; ++gg) {
    f32x4 s = (f32x4){0.f, 0.f, 0.f, 0.f};
    #pragma unroll
    for (int ks = 0; ks < 8; ++ks)
      s += *(const f32x4*)(ws + GATE_PART + (size_t)ks * 524288 + (size_t)b * 8192 + gg * 2048 + j4);
    g[gg] = s;
  }
  f32x4 ysum = (f32x4){0.f, 0.f, 0.f, 0.f};
  #pragma unroll
  for (int ks = 0; ks < 8; ++ks)
    ysum += *(const f32x4*)(ws + Y_PART + (size_t)ks * 131072 + (size_t)b * 2048 + j4);

  const f32x4 cp = *(const f32x4*)(c_prev + (size_t)b * 2048 + j4);
  f32x4 hF, cF;
  #pragma unroll
  for (int e = 0; e < 4; ++e) {
    float f  = fsigmoid(g[0][e]);
    float i  = fsigmoid(g[1][e]);
    float ct = ftanh(g[2][e]);
    float o  = fsigmoid(g[3][e]);
    float c  = f * cp[e] + i * ct;
    cF[e] = c;
    hF[e] = o * ftanh(c);
  }
  float* ob = out + (size_t)b * 6144;
  *(f32x4*)(ob + j4)        = ysum;   // y = h_prev @ Wy + by
  *(f32x4*)(ob + 2048 + j4) = hF;     // h
  *(f32x4*)(ob + 4096 + j4) = cF;     // c
}

extern "C" void kernel_launch(void* const* d_in, const int* in_sizes, int n_in,
                              void* d_out, int out_size, void* d_ws, size_t ws_size,
                              hipStream_t stream)
{
  const float* X   = (const float*)d_in[0];
  const float* H   = (const float*)d_in[1];
  const float* Cp  = (const float*)d_in[2];
  const float* Wfh = (const float*)d_in[3];
  const float* Wfx = (const float*)d_in[4];
  const float* bfp = (const float*)d_in[5];
  const float* Wih = (const float*)d_in[6];
  const float* Wix = (const float*)d_in[7];
  const float* bip = (const float*)d_in[8];
  const float* Woh = (const float*)d_in[9];
  const float* Wox = (const float*)d_in[10];
  const float* bop = (const float*)d_in[11];
  const float* Wch = (const float*)d_in[12];
  const float* Wcx = (const float*)d_in[13];
  const float* bcp = (const float*)d_in[14];
  const float* Wy  = (const float*)d_in[15];
  const float* by  = (const float*)d_in[16];
  float* ws  = (float*)d_ws;
  float* out = (float*)d_out;

  lstm_aconv<<<128, 256, 0, stream>>>(X, H, (ushort*)(ws + ABF_OFF));
  lstm_gemm<<<640, 256, 0, stream>>>(Wfh, Wfx, bfp, Wih, Wix, bip,
                                     Woh, Wox, bop, Wch, Wcx, bcp, Wy, by, ws);
  lstm_combine<<<512, 64, 0, stream>>>(ws, Cp, out);
}